// Round 1
// baseline (1682.604 us; speedup 1.0000x reference)
//
#include <hip/hip_runtime.h>
#include <hip/hip_bf16.h>
#include <stdint.h>

#define U_N   100000
#define I_N   200000
#define NN    300000
#define DD    64
#define NNZ_N 6400000
#define BB    4096
#define CHUNK 4096
#define NB    ((NN + CHUNK - 1) / CHUNK)   // 74

typedef unsigned short u16;
typedef unsigned int   u32;

__device__ __forceinline__ u16 f2bf(float f) {
    u32 u = __float_as_uint(f);
    u32 r = (u + 0x7FFFu + ((u >> 16) & 1u)) >> 16;
    return (u16)r;
}

// ---------------- CSR build ----------------

__global__ void hist_k(const int* __restrict__ row, int* __restrict__ cnt) {
    int i = blockIdx.x * blockDim.x + threadIdx.x;
    if (i < NNZ_N) atomicAdd(&cnt[row[i]], 1);
}

__global__ void scan1_k(const int* __restrict__ cnt, int* __restrict__ bsums) {
    __shared__ int red[256];
    int base = blockIdx.x * CHUNK;
    int s = 0;
    for (int j = threadIdx.x; j < CHUNK; j += 256) {
        int idx = base + j;
        s += (idx < NN) ? cnt[idx] : 0;
    }
    red[threadIdx.x] = s;
    __syncthreads();
    for (int o = 128; o > 0; o >>= 1) {
        if (threadIdx.x < o) red[threadIdx.x] += red[threadIdx.x + o];
        __syncthreads();
    }
    if (threadIdx.x == 0) bsums[blockIdx.x] = red[0];
}

__global__ void scan2_k(int* __restrict__ bsums, int* __restrict__ row_ptr) {
    __shared__ int sh[128];
    int v = (threadIdx.x < NB) ? bsums[threadIdx.x] : 0;
    sh[threadIdx.x] = v;
    __syncthreads();
    for (int o = 1; o < 128; o <<= 1) {
        int t = (threadIdx.x >= o) ? sh[threadIdx.x - o] : 0;
        __syncthreads();
        sh[threadIdx.x] += t;
        __syncthreads();
    }
    if (threadIdx.x < NB) bsums[threadIdx.x] = sh[threadIdx.x] - v;  // exclusive
    if (threadIdx.x == 127) row_ptr[NN] = sh[127];                   // total = NNZ
}

__global__ void scan3_k(const int* __restrict__ cnt, const int* __restrict__ bsums,
                        int* __restrict__ row_ptr, int* __restrict__ cursor) {
    __shared__ int tsum[256];
    int base = blockIdx.x * CHUNK;
    int loc[16];
    int s = 0;
#pragma unroll
    for (int j = 0; j < 16; j++) {
        int idx = base + threadIdx.x * 16 + j;
        int c = (idx < NN) ? cnt[idx] : 0;
        loc[j] = s;
        s += c;
    }
    tsum[threadIdx.x] = s;
    __syncthreads();
    int v = s;
    for (int o = 1; o < 256; o <<= 1) {
        int t = (threadIdx.x >= o) ? tsum[threadIdx.x - o] : 0;
        __syncthreads();
        tsum[threadIdx.x] += t;
        __syncthreads();
    }
    int texcl = tsum[threadIdx.x] - v;
    int boff = bsums[blockIdx.x];
#pragma unroll
    for (int j = 0; j < 16; j++) {
        int idx = base + threadIdx.x * 16 + j;
        if (idx < NN) {
            int rp = boff + texcl + loc[j];
            row_ptr[idx] = rp;
            cursor[idx]  = rp;
        }
    }
}

__global__ void scatter_k(const int* __restrict__ row, const int* __restrict__ col,
                          const float* __restrict__ val, int* __restrict__ cursor,
                          int* __restrict__ col_s, float* __restrict__ val_s) {
    int i = blockIdx.x * blockDim.x + threadIdx.x;
    if (i < NNZ_N) {
        int r = row[i];
        int p = atomicAdd(&cursor[r], 1);
        col_s[p] = col[i];
        val_s[p] = val[i];
    }
}

// ---------------- feature pack (online|target -> bf16 [N,128]) ----------------

__global__ void pack_k(const float* __restrict__ ue_on, const float* __restrict__ ie_on,
                       const float* __restrict__ ue_tg, const float* __restrict__ ie_tg,
                       u16* __restrict__ x0) {
    int t = blockIdx.x * blockDim.x + threadIdx.x;   // NN*32 threads
    int n = t >> 5;
    int j = t & 31;
    if (n >= NN) return;
    const float* src;
    int soff, doff;
    if (j < 16) {
        soff = j * 4; doff = j * 4;
        src = (n < U_N) ? ue_on + (size_t)n * 64 : ie_on + (size_t)(n - U_N) * 64;
    } else {
        soff = (j - 16) * 4; doff = 64 + (j - 16) * 4;
        src = (n < U_N) ? ue_tg + (size_t)n * 64 : ie_tg + (size_t)(n - U_N) * 64;
    }
    float4 f = *(const float4*)(src + soff);
    ushort4 o;
    o.x = f2bf(f.x); o.y = f2bf(f.y); o.z = f2bf(f.z); o.w = f2bf(f.w);
    *(ushort4*)(x0 + (size_t)n * 128 + doff) = o;
}

// ---------------- SpMM: row-per-wave, bf16 in/out, fp32 accumulate ----------------

__global__ __launch_bounds__(256) void spmm_k(const int* __restrict__ row_ptr,
                                              const int* __restrict__ col_s,
                                              const float* __restrict__ val_s,
                                              const u16* __restrict__ x,
                                              u16* __restrict__ y) {
    int wave = threadIdx.x >> 6;
    int lane = threadIdx.x & 63;
    int r = blockIdx.x * 4 + wave;
    if (r >= NN) return;
    int e0 = row_ptr[r], e1 = row_ptr[r + 1];
    float ax0 = 0.f, ay0 = 0.f, ax1 = 0.f, ay1 = 0.f;
    int e = e0;
    for (; e + 2 <= e1; e += 2) {
        int c0 = col_s[e], c1 = col_s[e + 1];
        float v0 = val_s[e], v1 = val_s[e + 1];
        u32 p0 = *(const u32*)(x + (size_t)c0 * 128 + (lane << 1));
        u32 p1 = *(const u32*)(x + (size_t)c1 * 128 + (lane << 1));
        float f0x = __uint_as_float(p0 << 16);
        float f0y = __uint_as_float(p0 & 0xFFFF0000u);
        float f1x = __uint_as_float(p1 << 16);
        float f1y = __uint_as_float(p1 & 0xFFFF0000u);
        ax0 += v0 * f0x; ay0 += v0 * f0y;
        ax1 += v1 * f1x; ay1 += v1 * f1y;
    }
    if (e < e1) {
        int c0 = col_s[e];
        float v0 = val_s[e];
        u32 p0 = *(const u32*)(x + (size_t)c0 * 128 + (lane << 1));
        ax0 += v0 * __uint_as_float(p0 << 16);
        ay0 += v0 * __uint_as_float(p0 & 0xFFFF0000u);
    }
    float ax = ax0 + ax1, ay = ay0 + ay1;
    u32 o = ((u32)f2bf(ay) << 16) | (u32)f2bf(ax);
    *(u32*)(y + (size_t)r * 128 + (lane << 1)) = o;
}

// last layer: only the 8192 gathered rows, fp32 accumulate straight into out_acc
__global__ __launch_bounds__(256) void spmm_last_k(const int* __restrict__ row_ptr,
                                                   const int* __restrict__ col_s,
                                                   const float* __restrict__ val_s,
                                                   const u16* __restrict__ x,
                                                   const int* __restrict__ user_idx,
                                                   const int* __restrict__ item_idx,
                                                   float* __restrict__ out_acc) {
    int wave = threadIdx.x >> 6;
    int lane = threadIdx.x & 63;
    int slot = blockIdx.x * 4 + wave;
    if (slot >= 2 * BB) return;
    int r = (slot < BB) ? user_idx[slot] : U_N + item_idx[slot - BB];
    int e0 = row_ptr[r], e1 = row_ptr[r + 1];
    float ax = 0.f, ay = 0.f;
    for (int e = e0; e < e1; ++e) {
        int c = col_s[e];
        float v = val_s[e];
        u32 p = *(const u32*)(x + (size_t)c * 128 + (lane << 1));
        ax += v * __uint_as_float(p << 16);
        ay += v * __uint_as_float(p & 0xFFFF0000u);
    }
    float2* p = (float2*)(out_acc + (size_t)slot * 128) + lane;
    float2 cur = *p;
    cur.x += ax; cur.y += ay;
    *p = cur;
}

// ---------------- gathered accumulator ----------------

__global__ void init_acc_k(const int* __restrict__ user_idx, const int* __restrict__ item_idx,
                           const float* __restrict__ ue_on, const float* __restrict__ ie_on,
                           const float* __restrict__ ue_tg, const float* __restrict__ ie_tg,
                           float* __restrict__ out_acc) {
    int t = blockIdx.x * blockDim.x + threadIdx.x;   // 2B*32 threads
    int slot = t >> 5;
    int j = t & 31;
    if (slot >= 2 * BB) return;
    int node = (slot < BB) ? user_idx[slot] : U_N + item_idx[slot - BB];
    const float* src;
    int soff, doff;
    if (j < 16) {
        soff = j * 4; doff = j * 4;
        src = (node < U_N) ? ue_on + (size_t)node * 64 : ie_on + (size_t)(node - U_N) * 64;
    } else {
        soff = (j - 16) * 4; doff = 64 + (j - 16) * 4;
        src = (node < U_N) ? ue_tg + (size_t)node * 64 : ie_tg + (size_t)(node - U_N) * 64;
    }
    float4 f = *(const float4*)(src + soff);
    *(float4*)(out_acc + (size_t)slot * 128 + doff) = f;
}

__global__ void gadd_k(const int* __restrict__ user_idx, const int* __restrict__ item_idx,
                       const u16* __restrict__ x, float* __restrict__ out_acc) {
    int t = blockIdx.x * blockDim.x + threadIdx.x;   // 2B*64 threads
    int slot = t >> 6;
    int l = t & 63;
    if (slot >= 2 * BB) return;
    int node = (slot < BB) ? user_idx[slot] : U_N + item_idx[slot - BB];
    u32 p = *(const u32*)(x + (size_t)node * 128 + (l << 1));
    float fx = __uint_as_float(p << 16);
    float fy = __uint_as_float(p & 0xFFFF0000u);
    float2* q = (float2*)(out_acc + (size_t)slot * 128) + l;
    float2 cur = *q;
    cur.x += fx; cur.y += fy;
    *q = cur;
}

// ---------------- epilogue ----------------

__global__ void targets_k(const float* __restrict__ out_acc, float* __restrict__ out) {
    int t = blockIdx.x * blockDim.x + threadIdx.x;   // 2B*16 threads
    int slot = t >> 4;
    int j = t & 15;
    if (slot >= 2 * BB) return;
    float4 f = *(const float4*)(out_acc + (size_t)slot * 128 + 64 + j * 4);
    f.x *= 0.25f; f.y *= 0.25f; f.z *= 0.25f; f.w *= 0.25f;
    size_t dst = (slot < BB) ? (size_t)BB * 64 + (size_t)slot * 64
                             : (size_t)3 * BB * 64 + (size_t)(slot - BB) * 64;
    *(float4*)(out + dst + j * 4) = f;
}

__global__ __launch_bounds__(256) void pred_k(const float* __restrict__ out_acc,
                                              const float* __restrict__ W,
                                              const float* __restrict__ bias,
                                              float* __restrict__ out) {
    __shared__ float wld[64 * 65];   // W transposed, padded: wld[k*65+j] = W[j*64+k]
    __shared__ float uld[4 * 64];
    int j = threadIdx.x & 63;
    int rl = threadIdx.x >> 6;
    for (int i = threadIdx.x; i < 4096; i += 256) {
        int jj = i >> 6, kk = i & 63;
        wld[kk * 65 + jj] = W[i];
    }
    int slot = blockIdx.x * 4 + rl;
    uld[rl * 64 + j] = out_acc[(size_t)slot * 128 + j] * 0.25f;
    __syncthreads();
    float acc = bias[j];
#pragma unroll
    for (int k = 0; k < 64; k++) acc += uld[rl * 64 + k] * wld[k * 65 + j];
    size_t dst = (slot < BB) ? (size_t)slot * 64 + j
                             : (size_t)2 * BB * 64 + (size_t)(slot - BB) * 64 + j;
    out[dst] = acc;
}

// ---------------- launch ----------------

extern "C" void kernel_launch(void* const* d_in, const int* in_sizes, int n_in,
                              void* d_out, int out_size, void* d_ws, size_t ws_size,
                              hipStream_t stream) {
    const float* ue_on = (const float*)d_in[0];
    const float* ie_on = (const float*)d_in[1];
    const float* ue_tg = (const float*)d_in[2];
    const float* ie_tg = (const float*)d_in[3];
    const float* adj_val = (const float*)d_in[4];
    const float* pred_w = (const float*)d_in[5];
    const float* pred_b = (const float*)d_in[6];
    const int* adj_row = (const int*)d_in[7];
    const int* adj_col = (const int*)d_in[8];
    const int* user_idx = (const int*)d_in[9];
    const int* item_idx = (const int*)d_in[10];
    float* out = (float*)d_out;

    char* ws = (char*)d_ws;
    size_t off = 0;
    auto alloc = [&](size_t bytes) -> char* {
        char* p = ws + off;
        off = (off + bytes + 255) & ~(size_t)255;
        return p;
    };
    int*   cnt     = (int*)alloc((size_t)NN * 4);
    int*   row_ptr = (int*)alloc((size_t)(NN + 1) * 4);
    int*   cursor  = (int*)alloc((size_t)NN * 4);
    int*   bsums   = (int*)alloc(256 * 4);
    int*   col_s   = (int*)alloc((size_t)NNZ_N * 4);
    float* val_s   = (float*)alloc((size_t)NNZ_N * 4);
    u16*   x_a     = (u16*)alloc((size_t)NN * 128 * 2);
    u16*   x_b     = (u16*)alloc((size_t)NN * 128 * 2);
    float* out_acc = (float*)alloc((size_t)2 * BB * 128 * 4);

    (void)n_in; (void)in_sizes; (void)out_size; (void)ws_size;

    // 1. CSR build
    hipMemsetAsync(cnt, 0, (size_t)NN * 4, stream);
    hist_k<<<NNZ_N / 256, 256, 0, stream>>>(adj_row, cnt);
    scan1_k<<<NB, 256, 0, stream>>>(cnt, bsums);
    scan2_k<<<1, 128, 0, stream>>>(bsums, row_ptr);
    scan3_k<<<NB, 256, 0, stream>>>(cnt, bsums, row_ptr, cursor);
    scatter_k<<<NNZ_N / 256, 256, 0, stream>>>(adj_row, adj_col, adj_val, cursor, col_s, val_s);

    // 2. pack x0 (bf16 [N,128]) and init gathered accumulator from fp32 embeddings
    pack_k<<<(NN * 32) / 256 + 1, 256, 0, stream>>>(ue_on, ie_on, ue_tg, ie_tg, x_a);
    init_acc_k<<<(2 * BB * 32) / 256, 256, 0, stream>>>(user_idx, item_idx, ue_on, ie_on, ue_tg, ie_tg, out_acc);

    // 3. layer 1 (full), layer 2 (full), layer 3 (restricted to gathered rows)
    spmm_k<<<NN / 4, 256, 0, stream>>>(row_ptr, col_s, val_s, x_a, x_b);
    gadd_k<<<(2 * BB * 64) / 256, 256, 0, stream>>>(user_idx, item_idx, x_b, out_acc);
    spmm_k<<<NN / 4, 256, 0, stream>>>(row_ptr, col_s, val_s, x_b, x_a);
    gadd_k<<<(2 * BB * 64) / 256, 256, 0, stream>>>(user_idx, item_idx, x_a, out_acc);
    spmm_last_k<<<(2 * BB) / 4, 256, 0, stream>>>(row_ptr, col_s, val_s, x_a, user_idx, item_idx, out_acc);

    // 4. epilogue
    targets_k<<<(2 * BB * 16) / 256, 256, 0, stream>>>(out_acc, out);
    pred_k<<<(2 * BB) / 4, 256, 0, stream>>>(out_acc, pred_w, pred_b, out);
}

// Round 2
// 1597.724 us; speedup vs baseline: 1.0531x; 1.0531x over previous
//
#include <hip/hip_runtime.h>
#include <hip/hip_bf16.h>
#include <stdint.h>

#define U_N   100000
#define I_N   200000
#define NN    300000
#define DD    64
#define NNZ_N 6400000
#define BB    4096
#define CHUNK 4096
#define NB    ((NN + CHUNK - 1) / CHUNK)   // 74 scan blocks
#define NBK   74                           // buckets of 4096 rows
#define EPB   4096                         // edges per pass-1 block

typedef unsigned short u16;
typedef unsigned int   u32;

__device__ __forceinline__ u16 f2bf(float f) {
    u32 u = __float_as_uint(f);
    u32 r = (u + 0x7FFFu + ((u >> 16) & 1u)) >> 16;
    return (u16)r;
}

// ---------------- CSR build: histogram + scan ----------------

__global__ void hist_k(const int* __restrict__ row, int* __restrict__ cnt) {
    int i = blockIdx.x * blockDim.x + threadIdx.x;
    if (i < NNZ_N) atomicAdd(&cnt[row[i]], 1);
}

__global__ void scan1_k(const int* __restrict__ cnt, int* __restrict__ bsums) {
    __shared__ int red[256];
    int base = blockIdx.x * CHUNK;
    int s = 0;
    for (int j = threadIdx.x; j < CHUNK; j += 256) {
        int idx = base + j;
        s += (idx < NN) ? cnt[idx] : 0;
    }
    red[threadIdx.x] = s;
    __syncthreads();
    for (int o = 128; o > 0; o >>= 1) {
        if (threadIdx.x < o) red[threadIdx.x] += red[threadIdx.x + o];
        __syncthreads();
    }
    if (threadIdx.x == 0) bsums[blockIdx.x] = red[0];
}

__global__ void scan2_k(int* __restrict__ bsums, int* __restrict__ row_ptr) {
    __shared__ int sh[128];
    int v = (threadIdx.x < NB) ? bsums[threadIdx.x] : 0;
    sh[threadIdx.x] = v;
    __syncthreads();
    for (int o = 1; o < 128; o <<= 1) {
        int t = (threadIdx.x >= o) ? sh[threadIdx.x - o] : 0;
        __syncthreads();
        sh[threadIdx.x] += t;
        __syncthreads();
    }
    if (threadIdx.x < NB) bsums[threadIdx.x] = sh[threadIdx.x] - v;  // exclusive
    if (threadIdx.x == 127) row_ptr[NN] = sh[127];                   // total = NNZ
}

__global__ void scan3_k(const int* __restrict__ cnt, const int* __restrict__ bsums,
                        int* __restrict__ row_ptr, int* __restrict__ cursor) {
    __shared__ int tsum[256];
    int base = blockIdx.x * CHUNK;
    int loc[16];
    int s = 0;
#pragma unroll
    for (int j = 0; j < 16; j++) {
        int idx = base + threadIdx.x * 16 + j;
        int c = (idx < NN) ? cnt[idx] : 0;
        loc[j] = s;
        s += c;
    }
    tsum[threadIdx.x] = s;
    __syncthreads();
    int v = s;
    for (int o = 1; o < 256; o <<= 1) {
        int t = (threadIdx.x >= o) ? tsum[threadIdx.x - o] : 0;
        __syncthreads();
        tsum[threadIdx.x] += t;
        __syncthreads();
    }
    int texcl = tsum[threadIdx.x] - v;
    int boff = bsums[blockIdx.x];
#pragma unroll
    for (int j = 0; j < 16; j++) {
        int idx = base + threadIdx.x * 16 + j;
        if (idx < NN) {
            int rp = boff + texcl + loc[j];
            row_ptr[idx] = rp;
            cursor[idx]  = rp;
        }
    }
}

__global__ void bkinit_k(const int* __restrict__ row_ptr, int* __restrict__ bkt_cursor) {
    int b = threadIdx.x;
    if (b < NBK) bkt_cursor[b] = row_ptr[b << 12];
}

// ---------------- pass 1: block-aggregated bucket scatter ----------------
// payload: pk = (row&4095)<<19 | col  (row_local 12b + col 19b = 31b), val separate

__global__ __launch_bounds__(256) void p1_k(const int* __restrict__ adj_row,
                                            const int* __restrict__ adj_col,
                                            const float* __restrict__ adj_val,
                                            int* __restrict__ bkt_cursor,
                                            u32* __restrict__ bpk,
                                            float* __restrict__ bval) {
    __shared__ int lcnt[NBK];
    __shared__ int lbase[NBK];
    int base = blockIdx.x * EPB;
    for (int i = threadIdx.x; i < NBK; i += 256) lcnt[i] = 0;
    __syncthreads();
    u32 pk[16]; float vv[16]; int bb[16]; int rk[16];
#pragma unroll
    for (int j = 0; j < 16; j++) {
        int e = base + j * 256 + threadIdx.x;
        bb[j] = -1;
        if (e < NNZ_N) {
            int r = adj_row[e];
            int c = adj_col[e];
            vv[j] = adj_val[e];
            int b = r >> 12;
            pk[j] = ((u32)(r & 4095) << 19) | (u32)c;
            bb[j] = b;
            rk[j] = atomicAdd(&lcnt[b], 1);
        }
    }
    __syncthreads();
    for (int i = threadIdx.x; i < NBK; i += 256)
        lbase[i] = atomicAdd(&bkt_cursor[i], lcnt[i]);
    __syncthreads();
#pragma unroll
    for (int j = 0; j < 16; j++) {
        if (bb[j] >= 0) {
            int p = lbase[bb[j]] + rk[j];
            bpk[p]  = pk[j];
            bval[p] = vv[j];
        }
    }
}

// ---------------- pass 2: within-bucket exact scatter (L2/L3-resident) ----------------

__global__ __launch_bounds__(256) void p2_k(const int* __restrict__ row_ptr,
                                            const u32* __restrict__ bpk,
                                            const float* __restrict__ bval,
                                            int* __restrict__ cursor,
                                            int2* __restrict__ edge_s) {
    int b = blockIdx.y;
    int e0 = row_ptr[b << 12];
    int e1 = (b == NBK - 1) ? NNZ_N : row_ptr[(b + 1) << 12];
    for (int e = e0 + blockIdx.x * 256 + threadIdx.x; e < e1; e += gridDim.x * 256) {
        u32 pk = bpk[e];
        float v = bval[e];
        int r = (b << 12) + (int)(pk >> 19);
        int c = (int)(pk & 0x7FFFFu);
        int slot = atomicAdd(&cursor[r], 1);
        edge_s[slot] = make_int2(c, __float_as_int(v));
    }
}

// ---------------- feature pack (online|target -> bf16 [N,128]) ----------------

__global__ void pack_k(const float* __restrict__ ue_on, const float* __restrict__ ie_on,
                       const float* __restrict__ ue_tg, const float* __restrict__ ie_tg,
                       u16* __restrict__ x0) {
    int t = blockIdx.x * blockDim.x + threadIdx.x;   // NN*32 threads
    int n = t >> 5;
    int j = t & 31;
    if (n >= NN) return;
    const float* src;
    int soff, doff;
    if (j < 16) {
        soff = j * 4; doff = j * 4;
        src = (n < U_N) ? ue_on + (size_t)n * 64 : ie_on + (size_t)(n - U_N) * 64;
    } else {
        soff = (j - 16) * 4; doff = 64 + (j - 16) * 4;
        src = (n < U_N) ? ue_tg + (size_t)n * 64 : ie_tg + (size_t)(n - U_N) * 64;
    }
    float4 f = *(const float4*)(src + soff);
    ushort4 o;
    o.x = f2bf(f.x); o.y = f2bf(f.y); o.z = f2bf(f.z); o.w = f2bf(f.w);
    *(ushort4*)(x0 + (size_t)n * 128 + doff) = o;
}

// ---------------- SpMM: row-per-wave, bf16 in/out, fp32 accumulate ----------------

__global__ __launch_bounds__(256) void spmm_k(const int* __restrict__ row_ptr,
                                              const int2* __restrict__ edge_s,
                                              const u16* __restrict__ x,
                                              u16* __restrict__ y) {
    int wave = threadIdx.x >> 6;
    int lane = threadIdx.x & 63;
    int r = blockIdx.x * 4 + wave;
    if (r >= NN) return;
    int e0 = row_ptr[r], e1 = row_ptr[r + 1];
    float ax0 = 0.f, ay0 = 0.f, ax1 = 0.f, ay1 = 0.f;
    float ax2 = 0.f, ay2 = 0.f, ax3 = 0.f, ay3 = 0.f;
    int e = e0;
    for (; e + 4 <= e1; e += 4) {
        int2 d0 = edge_s[e], d1 = edge_s[e + 1], d2 = edge_s[e + 2], d3 = edge_s[e + 3];
        u32 p0 = *(const u32*)(x + (size_t)d0.x * 128 + (lane << 1));
        u32 p1 = *(const u32*)(x + (size_t)d1.x * 128 + (lane << 1));
        u32 p2 = *(const u32*)(x + (size_t)d2.x * 128 + (lane << 1));
        u32 p3 = *(const u32*)(x + (size_t)d3.x * 128 + (lane << 1));
        float v0 = __int_as_float(d0.y), v1 = __int_as_float(d1.y);
        float v2 = __int_as_float(d2.y), v3 = __int_as_float(d3.y);
        ax0 += v0 * __uint_as_float(p0 << 16); ay0 += v0 * __uint_as_float(p0 & 0xFFFF0000u);
        ax1 += v1 * __uint_as_float(p1 << 16); ay1 += v1 * __uint_as_float(p1 & 0xFFFF0000u);
        ax2 += v2 * __uint_as_float(p2 << 16); ay2 += v2 * __uint_as_float(p2 & 0xFFFF0000u);
        ax3 += v3 * __uint_as_float(p3 << 16); ay3 += v3 * __uint_as_float(p3 & 0xFFFF0000u);
    }
    for (; e < e1; ++e) {
        int2 d0 = edge_s[e];
        float v0 = __int_as_float(d0.y);
        u32 p0 = *(const u32*)(x + (size_t)d0.x * 128 + (lane << 1));
        ax0 += v0 * __uint_as_float(p0 << 16);
        ay0 += v0 * __uint_as_float(p0 & 0xFFFF0000u);
    }
    float ax = (ax0 + ax1) + (ax2 + ax3);
    float ay = (ay0 + ay1) + (ay2 + ay3);
    u32 o = ((u32)f2bf(ay) << 16) | (u32)f2bf(ax);
    *(u32*)(y + (size_t)r * 128 + (lane << 1)) = o;
}

// last layer: only the 8192 gathered rows, fp32 accumulate straight into out_acc
__global__ __launch_bounds__(256) void spmm_last_k(const int* __restrict__ row_ptr,
                                                   const int2* __restrict__ edge_s,
                                                   const u16* __restrict__ x,
                                                   const int* __restrict__ user_idx,
                                                   const int* __restrict__ item_idx,
                                                   float* __restrict__ out_acc) {
    int wave = threadIdx.x >> 6;
    int lane = threadIdx.x & 63;
    int slot = blockIdx.x * 4 + wave;
    if (slot >= 2 * BB) return;
    int r = (slot < BB) ? user_idx[slot] : U_N + item_idx[slot - BB];
    int e0 = row_ptr[r], e1 = row_ptr[r + 1];
    float ax = 0.f, ay = 0.f;
    for (int e = e0; e < e1; ++e) {
        int2 d = edge_s[e];
        float v = __int_as_float(d.y);
        u32 p = *(const u32*)(x + (size_t)d.x * 128 + (lane << 1));
        ax += v * __uint_as_float(p << 16);
        ay += v * __uint_as_float(p & 0xFFFF0000u);
    }
    float2* p = (float2*)(out_acc + (size_t)slot * 128) + lane;
    float2 cur = *p;
    cur.x += ax; cur.y += ay;
    *p = cur;
}

// ---------------- gathered accumulator ----------------

__global__ void init_acc_k(const int* __restrict__ user_idx, const int* __restrict__ item_idx,
                           const float* __restrict__ ue_on, const float* __restrict__ ie_on,
                           const float* __restrict__ ue_tg, const float* __restrict__ ie_tg,
                           float* __restrict__ out_acc) {
    int t = blockIdx.x * blockDim.x + threadIdx.x;   // 2B*32 threads
    int slot = t >> 5;
    int j = t & 31;
    if (slot >= 2 * BB) return;
    int node = (slot < BB) ? user_idx[slot] : U_N + item_idx[slot - BB];
    const float* src;
    int soff, doff;
    if (j < 16) {
        soff = j * 4; doff = j * 4;
        src = (node < U_N) ? ue_on + (size_t)node * 64 : ie_on + (size_t)(node - U_N) * 64;
    } else {
        soff = (j - 16) * 4; doff = 64 + (j - 16) * 4;
        src = (node < U_N) ? ue_tg + (size_t)node * 64 : ie_tg + (size_t)(node - U_N) * 64;
    }
    float4 f = *(const float4*)(src + soff);
    *(float4*)(out_acc + (size_t)slot * 128 + doff) = f;
}

__global__ void gadd_k(const int* __restrict__ user_idx, const int* __restrict__ item_idx,
                       const u16* __restrict__ x, float* __restrict__ out_acc) {
    int t = blockIdx.x * blockDim.x + threadIdx.x;   // 2B*64 threads
    int slot = t >> 6;
    int l = t & 63;
    if (slot >= 2 * BB) return;
    int node = (slot < BB) ? user_idx[slot] : U_N + item_idx[slot - BB];
    u32 p = *(const u32*)(x + (size_t)node * 128 + (l << 1));
    float fx = __uint_as_float(p << 16);
    float fy = __uint_as_float(p & 0xFFFF0000u);
    float2* q = (float2*)(out_acc + (size_t)slot * 128) + l;
    float2 cur = *q;
    cur.x += fx; cur.y += fy;
    *q = cur;
}

// ---------------- epilogue ----------------

__global__ void targets_k(const float* __restrict__ out_acc, float* __restrict__ out) {
    int t = blockIdx.x * blockDim.x + threadIdx.x;   // 2B*16 threads
    int slot = t >> 4;
    int j = t & 15;
    if (slot >= 2 * BB) return;
    float4 f = *(const float4*)(out_acc + (size_t)slot * 128 + 64 + j * 4);
    f.x *= 0.25f; f.y *= 0.25f; f.z *= 0.25f; f.w *= 0.25f;
    size_t dst = (slot < BB) ? (size_t)BB * 64 + (size_t)slot * 64
                             : (size_t)3 * BB * 64 + (size_t)(slot - BB) * 64;
    *(float4*)(out + dst + j * 4) = f;
}

__global__ __launch_bounds__(256) void pred_k(const float* __restrict__ out_acc,
                                              const float* __restrict__ W,
                                              const float* __restrict__ bias,
                                              float* __restrict__ out) {
    __shared__ float wld[64 * 65];   // W transposed, padded
    __shared__ float uld[4 * 64];
    int j = threadIdx.x & 63;
    int rl = threadIdx.x >> 6;
    for (int i = threadIdx.x; i < 4096; i += 256) {
        int jj = i >> 6, kk = i & 63;
        wld[kk * 65 + jj] = W[i];
    }
    int slot = blockIdx.x * 4 + rl;
    uld[rl * 64 + j] = out_acc[(size_t)slot * 128 + j] * 0.25f;
    __syncthreads();
    float acc = bias[j];
#pragma unroll
    for (int k = 0; k < 64; k++) acc += uld[rl * 64 + k] * wld[k * 65 + j];
    size_t dst = (slot < BB) ? (size_t)slot * 64 + j
                             : (size_t)2 * BB * 64 + (size_t)(slot - BB) * 64 + j;
    out[dst] = acc;
}

// ---------------- launch ----------------

extern "C" void kernel_launch(void* const* d_in, const int* in_sizes, int n_in,
                              void* d_out, int out_size, void* d_ws, size_t ws_size,
                              hipStream_t stream) {
    const float* ue_on = (const float*)d_in[0];
    const float* ie_on = (const float*)d_in[1];
    const float* ue_tg = (const float*)d_in[2];
    const float* ie_tg = (const float*)d_in[3];
    const float* adj_val = (const float*)d_in[4];
    const float* pred_w = (const float*)d_in[5];
    const float* pred_b = (const float*)d_in[6];
    const int* adj_row = (const int*)d_in[7];
    const int* adj_col = (const int*)d_in[8];
    const int* user_idx = (const int*)d_in[9];
    const int* item_idx = (const int*)d_in[10];
    float* out = (float*)d_out;

    char* ws = (char*)d_ws;
    size_t off = 0;
    auto alloc = [&](size_t bytes) -> char* {
        char* p = ws + off;
        off = (off + bytes + 255) & ~(size_t)255;
        return p;
    };
    int*   cnt        = (int*)alloc((size_t)NN * 4);
    int*   row_ptr    = (int*)alloc((size_t)(NN + 1) * 4);
    int*   cursor     = (int*)alloc((size_t)NN * 4);
    int*   bsums      = (int*)alloc(256 * 4);
    int*   bkt_cursor = (int*)alloc(256 * 4);
    int2*  edge_s     = (int2*)alloc((size_t)NNZ_N * 8);
    u16*   x_a        = (u16*)alloc((size_t)NN * 128 * 2);
    u16*   x_b        = (u16*)alloc((size_t)NN * 128 * 2);
    float* out_acc    = (float*)alloc((size_t)2 * BB * 128 * 4);

    // bucket staging aliases x_a/x_b (dead until pack_k runs)
    u32*   bpk  = (u32*)x_a;     // 25.6 MB <= 76.8 MB
    float* bval = (float*)x_b;

    (void)n_in; (void)in_sizes; (void)out_size; (void)ws_size;

    // 1. CSR build
    hipMemsetAsync(cnt, 0, (size_t)NN * 4, stream);
    hist_k<<<NNZ_N / 256, 256, 0, stream>>>(adj_row, cnt);
    scan1_k<<<NB, 256, 0, stream>>>(cnt, bsums);
    scan2_k<<<1, 128, 0, stream>>>(bsums, row_ptr);
    scan3_k<<<NB, 256, 0, stream>>>(cnt, bsums, row_ptr, cursor);
    bkinit_k<<<1, 128, 0, stream>>>(row_ptr, bkt_cursor);
    p1_k<<<(NNZ_N + EPB - 1) / EPB, 256, 0, stream>>>(adj_row, adj_col, adj_val, bkt_cursor, bpk, bval);
    p2_k<<<dim3(64, NBK), 256, 0, stream>>>(row_ptr, bpk, bval, cursor, edge_s);

    // 2. pack x0 (bf16 [N,128]) and init gathered accumulator from fp32 embeddings
    pack_k<<<(NN * 32) / 256 + 1, 256, 0, stream>>>(ue_on, ie_on, ue_tg, ie_tg, x_a);
    init_acc_k<<<(2 * BB * 32) / 256, 256, 0, stream>>>(user_idx, item_idx, ue_on, ie_on, ue_tg, ie_tg, out_acc);

    // 3. layer 1 (full), layer 2 (full), layer 3 (restricted to gathered rows)
    spmm_k<<<NN / 4, 256, 0, stream>>>(row_ptr, edge_s, x_a, x_b);
    gadd_k<<<(2 * BB * 64) / 256, 256, 0, stream>>>(user_idx, item_idx, x_b, out_acc);
    spmm_k<<<NN / 4, 256, 0, stream>>>(row_ptr, edge_s, x_b, x_a);
    gadd_k<<<(2 * BB * 64) / 256, 256, 0, stream>>>(user_idx, item_idx, x_a, out_acc);
    spmm_last_k<<<(2 * BB) / 4, 256, 0, stream>>>(row_ptr, edge_s, x_a, user_idx, item_idx, out_acc);

    // 4. epilogue
    targets_k<<<(2 * BB * 16) / 256, 256, 0, stream>>>(out_acc, out);
    pred_k<<<(2 * BB) / 4, 256, 0, stream>>>(out_acc, pred_w, pred_b, out);
}

// Round 3
// 1167.464 us; speedup vs baseline: 1.4412x; 1.3685x over previous
//
#include <hip/hip_runtime.h>
#include <hip/hip_bf16.h>
#include <stdint.h>

#define U_N   100000
#define I_N   200000
#define NN    300000
#define DD    64
#define NNZ_N 6400000
#define BB    4096
#define CHUNK 4096
#define NB    ((NN + CHUNK - 1) / CHUNK)   // 74 scan blocks
#define NBK   74                           // coarse buckets of 4096 rows
#define EPB   4096                         // edges per pass-1 block
#define NSB   1184                         // 74*16 sub-buckets of 256 rows
#define SUBCAP 6656                        // max edges per sub-bucket (mean 5461, +16 sigma)

typedef unsigned short u16;
typedef unsigned int   u32;

__device__ __forceinline__ u16 f2bf(float f) {
    u32 u = __float_as_uint(f);
    u32 r = (u + 0x7FFFu + ((u >> 16) & 1u)) >> 16;
    return (u16)r;
}

// ---------------- CSR build: histogram + scan ----------------

__global__ void hist_k(const int* __restrict__ row, int* __restrict__ cnt) {
    int i = blockIdx.x * blockDim.x + threadIdx.x;
    if (i < NNZ_N) atomicAdd(&cnt[row[i]], 1);
}

__global__ void scan1_k(const int* __restrict__ cnt, int* __restrict__ bsums) {
    __shared__ int red[256];
    int base = blockIdx.x * CHUNK;
    int s = 0;
    for (int j = threadIdx.x; j < CHUNK; j += 256) {
        int idx = base + j;
        s += (idx < NN) ? cnt[idx] : 0;
    }
    red[threadIdx.x] = s;
    __syncthreads();
    for (int o = 128; o > 0; o >>= 1) {
        if (threadIdx.x < o) red[threadIdx.x] += red[threadIdx.x + o];
        __syncthreads();
    }
    if (threadIdx.x == 0) bsums[blockIdx.x] = red[0];
}

__global__ void scan2_k(int* __restrict__ bsums, int* __restrict__ row_ptr) {
    __shared__ int sh[128];
    int v = (threadIdx.x < NB) ? bsums[threadIdx.x] : 0;
    sh[threadIdx.x] = v;
    __syncthreads();
    for (int o = 1; o < 128; o <<= 1) {
        int t = (threadIdx.x >= o) ? sh[threadIdx.x - o] : 0;
        __syncthreads();
        sh[threadIdx.x] += t;
        __syncthreads();
    }
    if (threadIdx.x < NB) bsums[threadIdx.x] = sh[threadIdx.x] - v;  // exclusive
    if (threadIdx.x == 127) row_ptr[NN] = sh[127];                   // total = NNZ
}

__global__ void scan3_k(const int* __restrict__ cnt, const int* __restrict__ bsums,
                        int* __restrict__ row_ptr) {
    __shared__ int tsum[256];
    int base = blockIdx.x * CHUNK;
    int loc[16];
    int s = 0;
#pragma unroll
    for (int j = 0; j < 16; j++) {
        int idx = base + threadIdx.x * 16 + j;
        int c = (idx < NN) ? cnt[idx] : 0;
        loc[j] = s;
        s += c;
    }
    tsum[threadIdx.x] = s;
    __syncthreads();
    int v = s;
    for (int o = 1; o < 256; o <<= 1) {
        int t = (threadIdx.x >= o) ? tsum[threadIdx.x - o] : 0;
        __syncthreads();
        tsum[threadIdx.x] += t;
        __syncthreads();
    }
    int texcl = tsum[threadIdx.x] - v;
    int boff = bsums[blockIdx.x];
#pragma unroll
    for (int j = 0; j < 16; j++) {
        int idx = base + threadIdx.x * 16 + j;
        if (idx < NN) row_ptr[idx] = boff + texcl + loc[j];
    }
}

__global__ void bkinit_k(const int* __restrict__ row_ptr, int* __restrict__ bkt_cursor) {
    int b = threadIdx.x;
    if (b < NBK) bkt_cursor[b] = row_ptr[b << 12];
}

__global__ void bkinit2_k(const int* __restrict__ row_ptr, int* __restrict__ sub_cursor) {
    int s = blockIdx.x * blockDim.x + threadIdx.x;
    if (s < NSB) {
        int r = s << 8;
        sub_cursor[s] = row_ptr[(r < NN) ? r : NN];
    }
}

// ---------------- pass 1: block-aggregated coarse bucket scatter ----------------
// payload: pk = (row&4095)<<19 | col  (row_local 12b + col 19b = 31b), val separate

__global__ __launch_bounds__(256) void p1_k(const int* __restrict__ adj_row,
                                            const int* __restrict__ adj_col,
                                            const float* __restrict__ adj_val,
                                            int* __restrict__ bkt_cursor,
                                            u32* __restrict__ bpk,
                                            float* __restrict__ bval) {
    __shared__ int lcnt[NBK];
    __shared__ int lbase[NBK];
    int base = blockIdx.x * EPB;
    for (int i = threadIdx.x; i < NBK; i += 256) lcnt[i] = 0;
    __syncthreads();
    u32 pk[16]; float vv[16]; int bb[16]; int rk[16];
#pragma unroll
    for (int j = 0; j < 16; j++) {
        int e = base + j * 256 + threadIdx.x;
        bb[j] = -1;
        if (e < NNZ_N) {
            int r = adj_row[e];
            int c = adj_col[e];
            vv[j] = adj_val[e];
            int b = r >> 12;
            pk[j] = ((u32)(r & 4095) << 19) | (u32)c;
            bb[j] = b;
            rk[j] = atomicAdd(&lcnt[b], 1);
        }
    }
    __syncthreads();
    for (int i = threadIdx.x; i < NBK; i += 256)
        lbase[i] = atomicAdd(&bkt_cursor[i], lcnt[i]);
    __syncthreads();
#pragma unroll
    for (int j = 0; j < 16; j++) {
        if (bb[j] >= 0) {
            int p = lbase[bb[j]] + rk[j];
            bpk[p]  = pk[j];
            bval[p] = vv[j];
        }
    }
}

// ---------------- pass 2: refine coarse bucket -> 16 sub-buckets, LDS-staged dense writes ----

__global__ __launch_bounds__(256) void p2r_k(const int* __restrict__ row_ptr,
                                             const u32* __restrict__ bpk,
                                             const float* __restrict__ bval,
                                             int* __restrict__ sub_cursor,
                                             int2* __restrict__ mid) {
    __shared__ int lcnt[16], lbase[16], sbase[16];
    __shared__ int2 stage[4096];
    int b = blockIdx.y;
    int e0 = row_ptr[b << 12];
    int e1 = (b == NBK - 1) ? NNZ_N : row_ptr[(b + 1) << 12];
    int base = e0 + blockIdx.x * 4096;
    if (base >= e1) return;
    if (threadIdx.x < 16) lcnt[threadIdx.x] = 0;
    __syncthreads();
    u32 pk[16]; float vv[16]; int sb[16], rk[16];
#pragma unroll
    for (int j = 0; j < 16; j++) {
        int e = base + j * 256 + threadIdx.x;
        sb[j] = -1;
        if (e < e1) {
            pk[j] = bpk[e];
            vv[j] = bval[e];
            int s = (int)((pk[j] >> 27) & 15u);   // row_local >> 8
            sb[j] = s;
            rk[j] = atomicAdd(&lcnt[s], 1);
        }
    }
    __syncthreads();
    if (threadIdx.x == 0) {
        int acc = 0;
#pragma unroll
        for (int s = 0; s < 16; s++) { sbase[s] = acc; acc += lcnt[s]; }
    }
    if (threadIdx.x < 16)
        lbase[threadIdx.x] = atomicAdd(&sub_cursor[b * 16 + threadIdx.x], lcnt[threadIdx.x]);
    __syncthreads();
#pragma unroll
    for (int j = 0; j < 16; j++)
        if (sb[j] >= 0)
            stage[sbase[sb[j]] + rk[j]] = make_int2((int)pk[j], __float_as_int(vv[j]));
    __syncthreads();
    for (int s = 0; s < 16; s++) {
        int c = lcnt[s], gb = lbase[s], lb = sbase[s];
        for (int i = threadIdx.x; i < c; i += 256)
            mid[gb + i] = stage[lb + i];
    }
}

// ---------------- pass 3: exact row sort inside one sub-bucket (all in LDS) ----------------

__global__ __launch_bounds__(256) void p3_k(const int* __restrict__ row_ptr,
                                            const int2* __restrict__ mid,
                                            int2* __restrict__ edge_s) {
    __shared__ int rbase[256], rcur[256];
    __shared__ int2 stage[SUBCAP];
    int s = blockIdx.x;
    int r0 = s << 8;
    if (r0 >= NN) return;
    int r1 = min(r0 + 256, NN);
    int nr = r1 - r0;
    int ebase = row_ptr[r0];
    int eend  = row_ptr[r1];
    int cnt = eend - ebase;
    if (threadIdx.x < nr) {
        rbase[threadIdx.x] = row_ptr[r0 + threadIdx.x] - ebase;
        rcur[threadIdx.x] = 0;
    }
    __syncthreads();
    for (int i = threadIdx.x; i < cnt; i += 256) {
        int2 d = mid[ebase + i];
        u32 pk = (u32)d.x;
        int l = (int)((pk >> 19) & 255u);
        int pos = rbase[l] + atomicAdd(&rcur[l], 1);
        if (pos < SUBCAP) stage[pos] = make_int2((int)(pk & 0x7FFFFu), d.y);
    }
    __syncthreads();
    for (int i = threadIdx.x; i < cnt; i += 256) edge_s[ebase + i] = stage[i];
}

// ---------------- feature pack (online|target -> bf16 [N,128]) ----------------

__global__ void pack_k(const float* __restrict__ ue_on, const float* __restrict__ ie_on,
                       const float* __restrict__ ue_tg, const float* __restrict__ ie_tg,
                       u16* __restrict__ x0) {
    int t = blockIdx.x * blockDim.x + threadIdx.x;   // NN*32 threads
    int n = t >> 5;
    int j = t & 31;
    if (n >= NN) return;
    const float* src;
    int soff, doff;
    if (j < 16) {
        soff = j * 4; doff = j * 4;
        src = (n < U_N) ? ue_on + (size_t)n * 64 : ie_on + (size_t)(n - U_N) * 64;
    } else {
        soff = (j - 16) * 4; doff = 64 + (j - 16) * 4;
        src = (n < U_N) ? ue_tg + (size_t)n * 64 : ie_tg + (size_t)(n - U_N) * 64;
    }
    float4 f = *(const float4*)(src + soff);
    ushort4 o;
    o.x = f2bf(f.x); o.y = f2bf(f.y); o.z = f2bf(f.z); o.w = f2bf(f.w);
    *(ushort4*)(x0 + (size_t)n * 128 + doff) = o;
}

// ---------------- SpMM: row-per-wave, bf16 in/out, fp32 accumulate ----------------

__global__ __launch_bounds__(256) void spmm_k(const int* __restrict__ row_ptr,
                                              const int2* __restrict__ edge_s,
                                              const u16* __restrict__ x,
                                              u16* __restrict__ y) {
    int wave = threadIdx.x >> 6;
    int lane = threadIdx.x & 63;
    int r = blockIdx.x * 4 + wave;
    if (r >= NN) return;
    int e0 = row_ptr[r], e1 = row_ptr[r + 1];
    float ax0 = 0.f, ay0 = 0.f, ax1 = 0.f, ay1 = 0.f;
    float ax2 = 0.f, ay2 = 0.f, ax3 = 0.f, ay3 = 0.f;
    int e = e0;
    for (; e + 4 <= e1; e += 4) {
        int2 d0 = edge_s[e], d1 = edge_s[e + 1], d2 = edge_s[e + 2], d3 = edge_s[e + 3];
        u32 p0 = *(const u32*)(x + (size_t)d0.x * 128 + (lane << 1));
        u32 p1 = *(const u32*)(x + (size_t)d1.x * 128 + (lane << 1));
        u32 p2 = *(const u32*)(x + (size_t)d2.x * 128 + (lane << 1));
        u32 p3 = *(const u32*)(x + (size_t)d3.x * 128 + (lane << 1));
        float v0 = __int_as_float(d0.y), v1 = __int_as_float(d1.y);
        float v2 = __int_as_float(d2.y), v3 = __int_as_float(d3.y);
        ax0 += v0 * __uint_as_float(p0 << 16); ay0 += v0 * __uint_as_float(p0 & 0xFFFF0000u);
        ax1 += v1 * __uint_as_float(p1 << 16); ay1 += v1 * __uint_as_float(p1 & 0xFFFF0000u);
        ax2 += v2 * __uint_as_float(p2 << 16); ay2 += v2 * __uint_as_float(p2 & 0xFFFF0000u);
        ax3 += v3 * __uint_as_float(p3 << 16); ay3 += v3 * __uint_as_float(p3 & 0xFFFF0000u);
    }
    for (; e < e1; ++e) {
        int2 d0 = edge_s[e];
        float v0 = __int_as_float(d0.y);
        u32 p0 = *(const u32*)(x + (size_t)d0.x * 128 + (lane << 1));
        ax0 += v0 * __uint_as_float(p0 << 16);
        ay0 += v0 * __uint_as_float(p0 & 0xFFFF0000u);
    }
    float ax = (ax0 + ax1) + (ax2 + ax3);
    float ay = (ay0 + ay1) + (ay2 + ay3);
    u32 o = ((u32)f2bf(ay) << 16) | (u32)f2bf(ax);
    *(u32*)(y + (size_t)r * 128 + (lane << 1)) = o;
}

// last layer: only the 8192 gathered rows, fp32 accumulate straight into out_acc
__global__ __launch_bounds__(256) void spmm_last_k(const int* __restrict__ row_ptr,
                                                   const int2* __restrict__ edge_s,
                                                   const u16* __restrict__ x,
                                                   const int* __restrict__ user_idx,
                                                   const int* __restrict__ item_idx,
                                                   float* __restrict__ out_acc) {
    int wave = threadIdx.x >> 6;
    int lane = threadIdx.x & 63;
    int slot = blockIdx.x * 4 + wave;
    if (slot >= 2 * BB) return;
    int r = (slot < BB) ? user_idx[slot] : U_N + item_idx[slot - BB];
    int e0 = row_ptr[r], e1 = row_ptr[r + 1];
    float ax = 0.f, ay = 0.f;
    for (int e = e0; e < e1; ++e) {
        int2 d = edge_s[e];
        float v = __int_as_float(d.y);
        u32 p = *(const u32*)(x + (size_t)d.x * 128 + (lane << 1));
        ax += v * __uint_as_float(p << 16);
        ay += v * __uint_as_float(p & 0xFFFF0000u);
    }
    float2* p = (float2*)(out_acc + (size_t)slot * 128) + lane;
    float2 cur = *p;
    cur.x += ax; cur.y += ay;
    *p = cur;
}

// ---------------- gathered accumulator ----------------

__global__ void init_acc_k(const int* __restrict__ user_idx, const int* __restrict__ item_idx,
                           const float* __restrict__ ue_on, const float* __restrict__ ie_on,
                           const float* __restrict__ ue_tg, const float* __restrict__ ie_tg,
                           float* __restrict__ out_acc) {
    int t = blockIdx.x * blockDim.x + threadIdx.x;   // 2B*32 threads
    int slot = t >> 5;
    int j = t & 31;
    if (slot >= 2 * BB) return;
    int node = (slot < BB) ? user_idx[slot] : U_N + item_idx[slot - BB];
    const float* src;
    int soff, doff;
    if (j < 16) {
        soff = j * 4; doff = j * 4;
        src = (node < U_N) ? ue_on + (size_t)node * 64 : ie_on + (size_t)(node - U_N) * 64;
    } else {
        soff = (j - 16) * 4; doff = 64 + (j - 16) * 4;
        src = (node < U_N) ? ue_tg + (size_t)node * 64 : ie_tg + (size_t)(node - U_N) * 64;
    }
    float4 f = *(const float4*)(src + soff);
    *(float4*)(out_acc + (size_t)slot * 128 + doff) = f;
}

__global__ void gadd_k(const int* __restrict__ user_idx, const int* __restrict__ item_idx,
                       const u16* __restrict__ x, float* __restrict__ out_acc) {
    int t = blockIdx.x * blockDim.x + threadIdx.x;   // 2B*64 threads
    int slot = t >> 6;
    int l = t & 63;
    if (slot >= 2 * BB) return;
    int node = (slot < BB) ? user_idx[slot] : U_N + item_idx[slot - BB];
    u32 p = *(const u32*)(x + (size_t)node * 128 + (l << 1));
    float fx = __uint_as_float(p << 16);
    float fy = __uint_as_float(p & 0xFFFF0000u);
    float2* q = (float2*)(out_acc + (size_t)slot * 128) + l;
    float2 cur = *q;
    cur.x += fx; cur.y += fy;
    *q = cur;
}

// ---------------- epilogue ----------------

__global__ void targets_k(const float* __restrict__ out_acc, float* __restrict__ out) {
    int t = blockIdx.x * blockDim.x + threadIdx.x;   // 2B*16 threads
    int slot = t >> 4;
    int j = t & 15;
    if (slot >= 2 * BB) return;
    float4 f = *(const float4*)(out_acc + (size_t)slot * 128 + 64 + j * 4);
    f.x *= 0.25f; f.y *= 0.25f; f.z *= 0.25f; f.w *= 0.25f;
    size_t dst = (slot < BB) ? (size_t)BB * 64 + (size_t)slot * 64
                             : (size_t)3 * BB * 64 + (size_t)(slot - BB) * 64;
    *(float4*)(out + dst + j * 4) = f;
}

__global__ __launch_bounds__(256) void pred_k(const float* __restrict__ out_acc,
                                              const float* __restrict__ W,
                                              const float* __restrict__ bias,
                                              float* __restrict__ out) {
    __shared__ float wld[64 * 65];   // W transposed, padded
    __shared__ float uld[4 * 64];
    int j = threadIdx.x & 63;
    int rl = threadIdx.x >> 6;
    for (int i = threadIdx.x; i < 4096; i += 256) {
        int jj = i >> 6, kk = i & 63;
        wld[kk * 65 + jj] = W[i];
    }
    int slot = blockIdx.x * 4 + rl;
    uld[rl * 64 + j] = out_acc[(size_t)slot * 128 + j] * 0.25f;
    __syncthreads();
    float acc = bias[j];
#pragma unroll
    for (int k = 0; k < 64; k++) acc += uld[rl * 64 + k] * wld[k * 65 + j];
    size_t dst = (slot < BB) ? (size_t)slot * 64 + j
                             : (size_t)2 * BB * 64 + (size_t)(slot - BB) * 64 + j;
    out[dst] = acc;
}

// ---------------- launch ----------------

extern "C" void kernel_launch(void* const* d_in, const int* in_sizes, int n_in,
                              void* d_out, int out_size, void* d_ws, size_t ws_size,
                              hipStream_t stream) {
    const float* ue_on = (const float*)d_in[0];
    const float* ie_on = (const float*)d_in[1];
    const float* ue_tg = (const float*)d_in[2];
    const float* ie_tg = (const float*)d_in[3];
    const float* adj_val = (const float*)d_in[4];
    const float* pred_w = (const float*)d_in[5];
    const float* pred_b = (const float*)d_in[6];
    const int* adj_row = (const int*)d_in[7];
    const int* adj_col = (const int*)d_in[8];
    const int* user_idx = (const int*)d_in[9];
    const int* item_idx = (const int*)d_in[10];
    float* out = (float*)d_out;

    char* ws = (char*)d_ws;
    size_t off = 0;
    auto alloc = [&](size_t bytes) -> char* {
        char* p = ws + off;
        off = (off + bytes + 255) & ~(size_t)255;
        return p;
    };
    int*   cnt        = (int*)alloc((size_t)NN * 4);
    int*   row_ptr    = (int*)alloc((size_t)(NN + 1) * 4);
    int*   bsums      = (int*)alloc(256 * 4);
    int*   bkt_cursor = (int*)alloc(256 * 4);
    int*   sub_cursor = (int*)alloc((size_t)NSB * 4);
    int2*  edge_s     = (int2*)alloc((size_t)NNZ_N * 8);
    u16*   x_a        = (u16*)alloc((size_t)NN * 128 * 2);
    u16*   x_b        = (u16*)alloc((size_t)NN * 128 * 2);
    float* out_acc    = (float*)alloc((size_t)2 * BB * 128 * 4);

    // staging aliases (dead before pack_k / first spmm write):
    //   bpk  -> x_a [0, 25.6MB)
    //   bval -> x_b [0, 25.6MB) ; mid -> x_b [25.6MB, 76.8MB)
    u32*   bpk  = (u32*)x_a;
    float* bval = (float*)x_b;
    int2*  mid  = (int2*)((char*)x_b + (size_t)NNZ_N * 4);

    (void)n_in; (void)in_sizes; (void)out_size; (void)ws_size;

    // 1. CSR build (dense-write 3-pass bucket sort)
    hipMemsetAsync(cnt, 0, (size_t)NN * 4, stream);
    hist_k<<<NNZ_N / 256, 256, 0, stream>>>(adj_row, cnt);
    scan1_k<<<NB, 256, 0, stream>>>(cnt, bsums);
    scan2_k<<<1, 128, 0, stream>>>(bsums, row_ptr);
    scan3_k<<<NB, 256, 0, stream>>>(cnt, bsums, row_ptr);
    bkinit_k<<<1, 128, 0, stream>>>(row_ptr, bkt_cursor);
    bkinit2_k<<<(NSB + 255) / 256, 256, 0, stream>>>(row_ptr, sub_cursor);
    p1_k<<<(NNZ_N + EPB - 1) / EPB, 256, 0, stream>>>(adj_row, adj_col, adj_val, bkt_cursor, bpk, bval);
    p2r_k<<<dim3(24, NBK), 256, 0, stream>>>(row_ptr, bpk, bval, sub_cursor, mid);
    p3_k<<<NSB, 256, 0, stream>>>(row_ptr, mid, edge_s);

    // 2. pack x0 (bf16 [N,128]) and init gathered accumulator from fp32 embeddings
    pack_k<<<(NN * 32) / 256 + 1, 256, 0, stream>>>(ue_on, ie_on, ue_tg, ie_tg, x_a);
    init_acc_k<<<(2 * BB * 32) / 256, 256, 0, stream>>>(user_idx, item_idx, ue_on, ie_on, ue_tg, ie_tg, out_acc);

    // 3. layer 1 (full), layer 2 (full), layer 3 (restricted to gathered rows)
    spmm_k<<<NN / 4, 256, 0, stream>>>(row_ptr, edge_s, x_a, x_b);
    gadd_k<<<(2 * BB * 64) / 256, 256, 0, stream>>>(user_idx, item_idx, x_b, out_acc);
    spmm_k<<<NN / 4, 256, 0, stream>>>(row_ptr, edge_s, x_b, x_a);
    gadd_k<<<(2 * BB * 64) / 256, 256, 0, stream>>>(user_idx, item_idx, x_a, out_acc);
    spmm_last_k<<<(2 * BB) / 4, 256, 0, stream>>>(row_ptr, edge_s, x_a, user_idx, item_idx, out_acc);

    // 4. epilogue
    targets_k<<<(2 * BB * 16) / 256, 256, 0, stream>>>(out_acc, out);
    pred_k<<<(2 * BB) / 4, 256, 0, stream>>>(out_acc, pred_w, pred_b, out);
}